// Round 12
// baseline (460.920 us; speedup 1.0000x reference)
//
#include <hip/hip_runtime.h>
#include <hip/hip_bf16.h>

#define WW 128
#define GG 64
#define GN_EPS 1e-5f
#define SCAN_B 1024

typedef __attribute__((ext_vector_type(8))) short short8;
typedef __attribute__((ext_vector_type(4))) float floatx4;

__device__ inline float bfbits2f(short v) {
    return __uint_as_float(((unsigned)(unsigned short)v) << 16);
}
__device__ inline short f2bfbits(float f) {
    __hip_bfloat16 h = __float2bfloat16(f);
    return *reinterpret_cast<short*>(&h);
}

// ---------------- prep1: hist (4 edges/thread) U stats (64 rows) U cvt_w ----
__global__ __launch_bounds__(256) void prep1_kernel(
    const int* __restrict__ ei, int E, int* __restrict__ deg, int HB,
    const float* __restrict__ x, const int* __restrict__ batch, int N, int SB,
    float* __restrict__ gsum, float* __restrict__ gsumsq, float* __restrict__ gcnt,
    const float* __restrict__ w0, const float* __restrict__ w1,
    const float* __restrict__ w2, const float* __restrict__ w3,
    __hip_bfloat16* __restrict__ wdst)
{
    int bid = blockIdx.x;
    int tid = threadIdx.x;

    if (bid < HB) {
        int base = bid * 1024 + tid;
        int d0 = (base       < E) ? ei[(size_t)E + base]       : -1;
        int d1 = (base + 256 < E) ? ei[(size_t)E + base + 256] : -1;
        int d2 = (base + 512 < E) ? ei[(size_t)E + base + 512] : -1;
        int d3 = (base + 768 < E) ? ei[(size_t)E + base + 768] : -1;
        if (d0 >= 0) atomicAdd(&deg[d0], 1);
        if (d1 >= 0) atomicAdd(&deg[d1], 1);
        if (d2 >= 0) atomicAdd(&deg[d2], 1);
        if (d3 >= 0) atomicAdd(&deg[d3], 1);
        return;
    }
    if (bid < HB + SB) {
        int sb = bid - HB;
        int half = tid >> 7;
        int w = tid & 127;
        int row0 = sb * 64 + half * 32;
        if (row0 >= N) return;
        int row1 = min(row0 + 32, N);
        float s = 0.f, ss = 0.f;
        int cur = batch[row0];
        int cnt = 0;
        auto flush = [&]() {
            atomicAdd(&gsum[cur * WW + w], s);
            atomicAdd(&gsumsq[cur * WW + w], ss);
            if (w == 0) atomicAdd(&gcnt[cur], (float)cnt);
            s = 0.f; ss = 0.f; cnt = 0;
        };
        int i = row0;
        for (; i + 4 <= row1; i += 4) {
            int g0 = batch[i + 0], g1 = batch[i + 1], g2 = batch[i + 2], g3 = batch[i + 3];
            float v0 = x[(size_t)(i + 0) * WW + w];
            float v1 = x[(size_t)(i + 1) * WW + w];
            float v2 = x[(size_t)(i + 2) * WW + w];
            float v3 = x[(size_t)(i + 3) * WW + w];
            if (g0 != cur) { flush(); cur = g0; }
            s += v0; ss += v0 * v0; ++cnt;
            if (g1 != cur) { flush(); cur = g1; }
            s += v1; ss += v1 * v1; ++cnt;
            if (g2 != cur) { flush(); cur = g2; }
            s += v2; ss += v2 * v2; ++cnt;
            if (g3 != cur) { flush(); cur = g3; }
            s += v3; ss += v3 * v3; ++cnt;
        }
        for (; i < row1; ++i) {
            int g = batch[i];
            float v = x[(size_t)i * WW + w];
            if (g != cur) { flush(); cur = g; }
            s += v; ss += v * v; ++cnt;
        }
        flush();
        return;
    }
    int idx = (bid - HB - SB) * 256 + tid;        // 0 .. 65535
    int m = idx >> 14;
    int o = idx & 16383;
    const float* src = (m == 0) ? w0 : (m == 1) ? w1 : (m == 2) ? w2 : w3;
    wdst[idx] = __float2bfloat16(src[o]);
}

// ---------------- scan2: block-local scan U finalize (independent chains) ----
__global__ __launch_bounds__(SCAN_B) void scan2_kernel(
    const int* __restrict__ deg, int N, int* __restrict__ off, int* __restrict__ bsum, int P,
    const float* __restrict__ gsum, const float* __restrict__ gsumsq,
    const float* __restrict__ gcnt,
    const float* __restrict__ wgt, const float* __restrict__ bias,
    const float* __restrict__ ms,
    float* __restrict__ scalev, float* __restrict__ shiftv)
{
    int bid = blockIdx.x;
    int t = threadIdx.x;
    if (bid < P) {
        __shared__ int s[SCAN_B];
        int i = bid * SCAN_B + t;
        int v = (i < N) ? deg[i] : 0;
        s[t] = v; __syncthreads();
        for (int d = 1; d < SCAN_B; d <<= 1) {
            int tmp = (t >= d) ? s[t - d] : 0;
            __syncthreads();
            s[t] += tmp;
            __syncthreads();
        }
        if (i < N) off[i] = s[t] - v;
        if (t == SCAN_B - 1) bsum[bid] = s[t];
        return;
    }
    int idx = (bid - P) * SCAN_B + t;
    if (idx >= GG * WW) return;
    int g = idx >> 7, w = idx & (WW - 1);
    float cnt = gcnt[g];
    float inv = cnt > 0.f ? 1.f / cnt : 0.f;
    float mean = gsum[idx] * inv;
    float msw = ms[w];
    float var = gsumsq[idx] * inv - mean * mean * msw * (2.f - msw);
    var = fmaxf(var, 0.f);
    float sc = wgt[w] * rsqrtf(var + GN_EPS);
    scalev[idx] = sc;
    shiftv[idx] = bias[w] - sc * msw * mean;
}

// add_offsets v3: 64-lane shfl reduction over bsum[0..bid) (one barrier)
__global__ __launch_bounds__(SCAN_B) void add_offsets2(
    int* __restrict__ off, const int* __restrict__ bsum, int N)
{
    __shared__ int red0;
    int t = threadIdx.x;
    if (t < 64) {
        int s = 0;
        for (int i = t; i < blockIdx.x; i += 64) s += bsum[i];
#pragma unroll
        for (int o = 32; o > 0; o >>= 1) s += __shfl_down(s, o, 64);
        if (t == 0) red0 = s;
    }
    __syncthreads();
    int i = blockIdx.x * SCAN_B + t;
    if (i < N) off[i] += red0;
}

// ---------------- place_norm: place (4 edges/thread) U normalize ----------
__global__ __launch_bounds__(256) void place_norm_kernel(
    const int* __restrict__ ei, const float* __restrict__ ew,
    const int* __restrict__ off, int* __restrict__ cursor,
    int2* __restrict__ ebuf, int E, int PB,
    const float* __restrict__ x, const int* __restrict__ batch,
    const float* __restrict__ scalev, const float* __restrict__ shiftv,
    __hip_bfloat16* __restrict__ xn, int N)
{
    int bid = blockIdx.x;
    int tid = threadIdx.x;

    if (bid < PB) {
        int base = bid * 1024 + tid;
        int dstv[4], srcv[4];
        float wv[4];
        int slot[4];
#pragma unroll
        for (int i = 0; i < 4; ++i) {
            int e = base + i * 256;
            dstv[i] = (e < E) ? ei[(size_t)E + e] : -1;
        }
#pragma unroll
        for (int i = 0; i < 4; ++i) {
            int e = base + i * 256;
            if (e < E) { srcv[i] = ei[e]; wv[i] = ew[e]; }
        }
#pragma unroll
        for (int i = 0; i < 4; ++i)
            if (dstv[i] >= 0) slot[i] = off[dstv[i]] + atomicAdd(&cursor[dstv[i]], 1);
#pragma unroll
        for (int i = 0; i < 4; ++i)
            if (dstv[i] >= 0) {
                unsigned long long v = (unsigned)srcv[i]
                    | ((unsigned long long)__float_as_uint(wv[i]) << 32);
                __builtin_nontemporal_store(v, (unsigned long long*)&ebuf[slot[i]]);
            }
        return;
    }
    // ---- normalize: one thread per 8 elems, 16B stores ----
    size_t nt = (size_t)(bid - PB) * 256 + tid;
    if (nt >= (size_t)N * (WW / 8)) return;
    int row = (int)(nt >> 4);
    int c8 = (int)(nt & 15) * 8;
    int g = batch[row];
    const float* xb = x + (size_t)row * WW + c8;
    const float* scb = scalev + (size_t)g * WW + c8;
    const float* shb = shiftv + (size_t)g * WW + c8;
    float4 v0 = *(const float4*)(xb);
    float4 v1 = *(const float4*)(xb + 4);
    float4 sc0 = *(const float4*)(scb);
    float4 sc1 = *(const float4*)(scb + 4);
    float4 sh0 = *(const float4*)(shb);
    float4 sh1 = *(const float4*)(shb + 4);
    union { short s[8]; uint4 u; } pk;
    pk.s[0] = f2bfbits(sc0.x * v0.x + sh0.x);
    pk.s[1] = f2bfbits(sc0.y * v0.y + sh0.y);
    pk.s[2] = f2bfbits(sc0.z * v0.z + sh0.z);
    pk.s[3] = f2bfbits(sc0.w * v0.w + sh0.w);
    pk.s[4] = f2bfbits(sc1.x * v1.x + sh1.x);
    pk.s[5] = f2bfbits(sc1.y * v1.y + sh1.y);
    pk.s[6] = f2bfbits(sc1.z * v1.z + sh1.z);
    pk.s[7] = f2bfbits(sc1.w * v1.w + sh1.w);
    *(uint4*)(xn + (size_t)row * WW + c8) = pk.u;
}

// ---------------- fused gather+GEMM v14: v13 + 8-wide gather unroll ---------
// R11: occupancy lever captured (50%, scheduler-settled); kernel remains
// latency/MLP-bound (4.9 TB/s effective fabric < ceiling). v14 doubles
// per-thread MLP in the dominant gather phase: 8 edges in flight (16
// independent 16B row loads) -> straggler rounds ceil(max_deg/8) ~= 2 vs 4.
// VGPR budget: 8x(a,b) = 64 + acc 16 + addr ~= 80-85, inside the 6-wave/EU
// cap (85); worst case compiler splits into 2x4 batches = current behavior.
// Overhang edges clamp to last (L1-hit) with weight 0. Everything else
// unchanged from v13 (R10/R11-verified).
// LDS swizzle (involution): slot s of row r holds chunk s^(r&15).
// C/D layout: col=lane&15, row=(lane>>4)*4+reg (m89-verified).
template <bool OUT_BF16>
__global__ __launch_bounds__(256, 6) void fused_kernel(
    const __hip_bfloat16* __restrict__ X,
    const int2* __restrict__ ebuf, const int* __restrict__ off,
    const int* __restrict__ deg,
    const __hip_bfloat16* __restrict__ Wrel, const __hip_bfloat16* __restrict__ Wroot,
    const float* __restrict__ bias, const float* __restrict__ resid,
    void* __restrict__ outv, int N, int leaky)
{
    __shared__ __align__(16) __hip_bfloat16 smem[2 * 32 * 128];   // 16 KB
    __shared__ __align__(16) int2 eshare[512];                    // 4 KB
    int tid = threadIdx.x;
    int wave = tid >> 6, lane = tid & 63;
    int q = lane >> 4, r16 = lane & 15;
    int rb = blockIdx.x * 32;

    // ---- (1a) A2 staging: 8 x 1KB instructions, 2 per wave (async) ----
#pragma unroll
    for (int s = 0; s < 2; ++s) {
        int t = wave * 2 + s;                     // 0..7, rows t*4..t*4+3
        int rloc = t * 4 + (lane >> 4);
        int c = (lane & 15) ^ (rloc & 15);        // pre-swizzled global chunk
        int grow = rb + rloc; if (grow >= N) grow = N - 1;
        const __hip_bfloat16* g = X + (size_t)grow * WW + c * 8;
        __hip_bfloat16* l = smem + 4096 + t * 512;   // linear LDS dest
        __builtin_amdgcn_global_load_lds(
            (const __attribute__((address_space(1))) void*)g,
            (__attribute__((address_space(3))) void*)l, 16, 0, 0);
    }

    // ---- (1b) ebuf slice staging: entries [e0, e0+nstage) -> eshare ----
    int endn = min(rb + 32, N) - 1;
    int e0 = off[rb];
    int ne = off[endn] + deg[endn] - e0;
    int nstage = min(ne, 512);
    {
        int pairs = (nstage + 1) >> 1;            // <= 256: one instr/thread
        if (tid < pairs) {
            const int2* g = ebuf + e0 + 2 * tid;
            int2* l = eshare + 2 * (wave * 64);
            __builtin_amdgcn_global_load_lds(
                (const __attribute__((address_space(1))) void*)g,
                (__attribute__((address_space(3))) void*)l, 16, 0, 0);
        }
    }
    __syncthreads();   // vmcnt(0): A2 + edge slice resident

    // ---- (2) gather: node = rb + tid>>3, cols (tid&7)*16..+15, 8-wide ----
    int node = rb + (tid >> 3);
    int nc = node < N ? node : N - 1;
    int start = off[nc];
    int d = (node < N) ? deg[nc] : 0;
    int lb = start - e0;                          // local index into eshare
    int sub = tid & 7;
    float a16[16];
#pragma unroll
    for (int j = 0; j < 16; ++j) a16[j] = 0.f;
    int last = d - 1;                             // d==0 -> loop skipped
    for (int k = 0; k <= last; k += 8) {
        int j1 = min(k + 1, last);
        int j2 = min(k + 2, last);
        int j3 = min(k + 3, last);
        int j4 = min(k + 4, last);
        int j5 = min(k + 5, last);
        int j6 = min(k + 6, last);
        int j7 = min(k + 7, last);
        int2 p0, p1, p2, p3, p4, p5, p6, p7;
        if (lb + j7 < nstage) {                   // common case: all staged
            p0 = eshare[lb + k];
            p1 = eshare[lb + j1];
            p2 = eshare[lb + j2];
            p3 = eshare[lb + j3];
            p4 = eshare[lb + j4];
            p5 = eshare[lb + j5];
            p6 = eshare[lb + j6];
            p7 = eshare[lb + j7];
        } else {                                  // ~never (block ne > 512)
            p0 = (lb + k  < nstage) ? eshare[lb + k]  : ebuf[start + k];
            p1 = (lb + j1 < nstage) ? eshare[lb + j1] : ebuf[start + j1];
            p2 = (lb + j2 < nstage) ? eshare[lb + j2] : ebuf[start + j2];
            p3 = (lb + j3 < nstage) ? eshare[lb + j3] : ebuf[start + j3];
            p4 = (lb + j4 < nstage) ? eshare[lb + j4] : ebuf[start + j4];
            p5 = (lb + j5 < nstage) ? eshare[lb + j5] : ebuf[start + j5];
            p6 = (lb + j6 < nstage) ? eshare[lb + j6] : ebuf[start + j6];
            p7 = (lb + j7 < nstage) ? eshare[lb + j7] : ebuf[start + j7];
        }
        const __hip_bfloat16* r0 = X + (size_t)p0.x * WW + sub * 16;
        const __hip_bfloat16* r1 = X + (size_t)p1.x * WW + sub * 16;
        const __hip_bfloat16* r2 = X + (size_t)p2.x * WW + sub * 16;
        const __hip_bfloat16* r3 = X + (size_t)p3.x * WW + sub * 16;
        const __hip_bfloat16* r4 = X + (size_t)p4.x * WW + sub * 16;
        const __hip_bfloat16* r5 = X + (size_t)p5.x * WW + sub * 16;
        const __hip_bfloat16* r6 = X + (size_t)p6.x * WW + sub * 16;
        const __hip_bfloat16* r7 = X + (size_t)p7.x * WW + sub * 16;
        short8 a0 = *(const short8*)(r0);
        short8 b0 = *(const short8*)(r0 + 8);
        short8 a1 = *(const short8*)(r1);
        short8 b1 = *(const short8*)(r1 + 8);
        short8 a2 = *(const short8*)(r2);
        short8 b2 = *(const short8*)(r2 + 8);
        short8 a3 = *(const short8*)(r3);
        short8 b3 = *(const short8*)(r3 + 8);
        short8 a4 = *(const short8*)(r4);
        short8 b4 = *(const short8*)(r4 + 8);
        short8 a5 = *(const short8*)(r5);
        short8 b5 = *(const short8*)(r5 + 8);
        short8 a6 = *(const short8*)(r6);
        short8 b6 = *(const short8*)(r6 + 8);
        short8 a7 = *(const short8*)(r7);
        short8 b7 = *(const short8*)(r7 + 8);
        float w0 = __int_as_float(p0.y);
        float w1 = (k + 1 <= last) ? __int_as_float(p1.y) : 0.f;
        float w2 = (k + 2 <= last) ? __int_as_float(p2.y) : 0.f;
        float w3 = (k + 3 <= last) ? __int_as_float(p3.y) : 0.f;
        float w4 = (k + 4 <= last) ? __int_as_float(p4.y) : 0.f;
        float w5 = (k + 5 <= last) ? __int_as_float(p5.y) : 0.f;
        float w6 = (k + 6 <= last) ? __int_as_float(p6.y) : 0.f;
        float w7 = (k + 7 <= last) ? __int_as_float(p7.y) : 0.f;
#pragma unroll
        for (int j = 0; j < 8; ++j) {
            float s0 = w0 * bfbits2f(a0[j]) + w1 * bfbits2f(a1[j])
                     + w2 * bfbits2f(a2[j]) + w3 * bfbits2f(a3[j]);
            float s1 = w4 * bfbits2f(a4[j]) + w5 * bfbits2f(a5[j])
                     + w6 * bfbits2f(a6[j]) + w7 * bfbits2f(a7[j]);
            a16[j] += s0 + s1;
            float t0 = w0 * bfbits2f(b0[j]) + w1 * bfbits2f(b1[j])
                     + w2 * bfbits2f(b2[j]) + w3 * bfbits2f(b3[j]);
            float t1 = w4 * bfbits2f(b4[j]) + w5 * bfbits2f(b5[j])
                     + w6 * bfbits2f(b6[j]) + w7 * bfbits2f(b7[j]);
            a16[8 + j] += t0 + t1;
        }
    }

    // ---- (3) agg -> A1 LDS region, swizzled (chunks 2*sub, 2*sub+1) ----
    {
        int r = tid >> 3;                          // local row 0..31
        short8 pk0, pk1;
#pragma unroll
        for (int j = 0; j < 8; ++j) {
            pk0[j] = f2bfbits(a16[j]);
            pk1[j] = f2bfbits(a16[8 + j]);
        }
        int s0 = (2 * sub)     ^ (r & 15);
        int s1 = (2 * sub + 1) ^ (r & 15);
        *(short8*)(smem + r * 128 + s0 * 8) = pk0;
        *(short8*)(smem + r * 128 + s1 * 8) = pk1;
    }

    // ---- W fragments: adjacent-pair cols (wave*32 + 2*r16 + tt) ----
    short8 wf[8][2];
#pragma unroll
    for (int kc = 0; kc < 8; ++kc) {
        const __hip_bfloat16* Wsel = (kc < 4) ? Wrel : Wroot;
        int koff = (kc & 3) * 32 + q * 8;
#pragma unroll
        for (int tt = 0; tt < 2; ++tt) {
            int col = wave * 32 + 2 * r16 + tt;
            wf[kc][tt] = *(const short8*)(Wsel + ((size_t)col * WW + koff));
        }
    }
    float bcol[2];
#pragma unroll
    for (int tt = 0; tt < 2; ++tt) bcol[tt] = bias[wave * 32 + 2 * r16 + tt];

    __syncthreads();   // drains lgkm (A1 written); A2 already resident

    // ---- (5) MFMA: kc<4 A1*Wrel, kc>=4 A2*Wroot ----
    floatx4 acc[2][2];
#pragma unroll
    for (int r = 0; r < 2; ++r)
#pragma unroll
        for (int tt = 0; tt < 2; ++tt) acc[r][tt] = (floatx4){0.f, 0.f, 0.f, 0.f};

#pragma unroll
    for (int kc = 0; kc < 8; ++kc) {
        int m = kc >> 2;
        short8 af[2];
#pragma unroll
        for (int r = 0; r < 2; ++r) {
            int row = r * 16 + r16;
            int slot = ((kc & 3) * 4 + q) ^ r16;       // row&15 == r16
            af[r] = *(const short8*)(&smem[m * 4096 + row * 128 + slot * 8]);
        }
#pragma unroll
        for (int r = 0; r < 2; ++r) {
            acc[r][0] = __builtin_amdgcn_mfma_f32_16x16x32_bf16(af[r], wf[kc][0], acc[r][0], 0, 0, 0);
            acc[r][1] = __builtin_amdgcn_mfma_f32_16x16x32_bf16(af[r], wf[kc][1], acc[r][1], 0, 0, 0);
        }
    }

    // ---- epilogue: packed adjacent-col stores ----
    int colb = wave * 32 + 2 * r16;
#pragma unroll
    for (int r = 0; r < 2; ++r)
#pragma unroll
        for (int rr = 0; rr < 4; ++rr) {
            int row = rb + r * 16 + q * 4 + rr;
            if (row < N) {
                float v0 = acc[r][0][rr] + bcol[0];
                float v1 = acc[r][1][rr] + bcol[1];
                if (leaky) {
                    v0 = v0 >= 0.f ? v0 : 0.1f * v0;
                    v1 = v1 >= 0.f ? v1 : 0.1f * v1;
                }
                if (OUT_BF16) {
                    __hip_bfloat162 o;
                    o.x = __float2bfloat16(v0);
                    o.y = __float2bfloat16(v1);
                    *(__hip_bfloat162*)((__hip_bfloat16*)outv + (size_t)row * WW + colb) = o;
                } else {
                    float2 rv = *(const float2*)(resid + (size_t)row * WW + colb);
                    float2 o;
                    o.x = v0 + rv.x;
                    o.y = v1 + rv.y;
                    *(float2*)((float*)outv + (size_t)row * WW + colb) = o;
                }
            }
        }
}

extern "C" void kernel_launch(void* const* d_in, const int* in_sizes, int n_in,
                              void* d_out, int out_size, void* d_ws, size_t ws_size,
                              hipStream_t stream) {
    const float* x      = (const float*)d_in[0];
    const int*   ei     = (const int*)d_in[1];
    const float* ew     = (const float*)d_in[2];
    const int*   batch  = (const int*)d_in[3];
    const float* gnw    = (const float*)d_in[4];
    const float* gnb    = (const float*)d_in[5];
    const float* gnm    = (const float*)d_in[6];
    const float* Wrel1  = (const float*)d_in[7];
    const float* brel1  = (const float*)d_in[8];
    const float* Wroot1 = (const float*)d_in[9];
    const float* Wrel2  = (const float*)d_in[10];
    const float* brel2  = (const float*)d_in[11];
    const float* Wroot2 = (const float*)d_in[12];

    int N = in_sizes[0] / WW;
    int E = in_sizes[1] / 2;
    int P = (N + SCAN_B - 1) / SCAN_B;           // 98
    int ntiles = (N + 31) / 32;                  // 3125
    int HB = (E + 1023) / 1024;                  // hist blocks
    int SB = (N + 63) / 64;                      // stats blocks
    int PB = (E + 1023) / 1024;                  // place blocks
    int FB2 = (GG * WW + SCAN_B - 1) / SCAN_B;   // finalize blocks @1024 (8)
    int NB = (int)(((size_t)N * (WW / 8) + 255) / 256);   // normalize blocks

    // workspace layout (8-byte aligned):
    // xn | y1 (bf16 N*W each) | Wb (bf16 4*W*W) | ebuf (int2 E)
    // | deg | cursor | gsum | gsumsq | gcnt | scalev | shiftv | off | bsum
    __hip_bfloat16* xn = (__hip_bfloat16*)d_ws;
    __hip_bfloat16* y1 = xn + (size_t)N * WW;
    __hip_bfloat16* Wb = y1 + (size_t)N * WW;
    int2* ebuf   = (int2*)(Wb + 4 * WW * WW);
    int*  deg    = (int*)(ebuf + E);
    int*  cursor = deg + N;
    float* gsum   = (float*)(cursor + N);
    float* gsumsq = gsum + GG * WW;
    float* gcnt   = gsumsq + GG * WW;
    float* scalev = gcnt + GG;
    float* shiftv = scalev + GG * WW;
    int*  off    = (int*)(shiftv + GG * WW);
    int*  bsum   = off + N;

    hipMemsetAsync(deg, 0, ((size_t)2 * N + 2 * GG * WW + GG) * sizeof(int), stream);

    // ---- prep1: hist U stats U cvt_w ----
    prep1_kernel<<<HB + SB + 256, 256, 0, stream>>>(
        ei, E, deg, HB,
        x, batch, N, SB, gsum, gsumsq, gcnt,
        Wrel1, Wroot1, Wrel2, Wroot2, Wb);

    // ---- scan2: block scan U finalize ----
    scan2_kernel<<<P + FB2, SCAN_B, 0, stream>>>(
        deg, N, off, bsum, P,
        gsum, gsumsq, gcnt, gnw, gnb, gnm, scalev, shiftv);

    add_offsets2<<<P, SCAN_B, 0, stream>>>(off, bsum, N);

    // ---- place U normalize ----
    place_norm_kernel<<<PB + NB, 256, 0, stream>>>(
        ei, ew, off, cursor, ebuf, E, PB,
        x, batch, scalev, shiftv, xn, N);

    // ---- layer 1: fused gather+GEMM (+bias+leaky) ----
    fused_kernel<true><<<ntiles, 256, 0, stream>>>(
        xn, ebuf, off, deg, Wb, Wb + WW * WW, brel1, nullptr, y1, N, 1);

    // ---- layer 2: fused gather+GEMM (+bias+residual) ----
    fused_kernel<false><<<ntiles, 256, 0, stream>>>(
        y1, ebuf, off, deg, Wb + 2 * WW * WW, Wb + 3 * WW * WW, brel2, x, d_out, N, 0);
}